// Round 12
// baseline (502.207 us; speedup 1.0000x reference)
//
#include <hip/hip_runtime.h>
#include <stdint.h>

// Problem dims (fixed by reference)
#define BDIM  4096
#define NIN   1024
#define NHID  4096
#define NOUT  1024

typedef unsigned short u16;
typedef unsigned int   u32;
typedef __attribute__((ext_vector_type(8))) __bf16 bf16x8;
typedef __attribute__((ext_vector_type(4))) float  f32x4;

__device__ __forceinline__ u16 f32_to_bf16_rne(float f) {
    u32 u = __builtin_bit_cast(u32, f);
    u = (u + 0x7fffu + ((u >> 16) & 1u)) >> 16;
    return (u16)u;
}
__device__ __forceinline__ float bf16_to_f32(u16 h) {
    u32 u = ((u32)h) << 16;
    return __builtin_bit_cast(float, u);
}

// ------------- fused pre-pass: cast x + transpose W1 + transpose W2 ---------
__device__ __forceinline__ void transpose_tile(
    const float* __restrict__ in, u16* __restrict__ out,
    int R, int C, int bx, int by, float (*tile)[33]) {
    const int rt = by * 32, ct = bx * 32;
    const int tid = threadIdx.x;
    {
        const int r  = tid >> 3;
        const int c4 = (tid & 7) * 4;
        float4 v = *(const float4*)(in + (size_t)(rt + r) * C + ct + c4);
        tile[r][c4 + 0] = v.x; tile[r][c4 + 1] = v.y;
        tile[r][c4 + 2] = v.z; tile[r][c4 + 3] = v.w;
    }
    __syncthreads();
    if (tid < 128) {
        const int oc = tid >> 2;
        const int ch = tid & 3;
        u16 tmp[8];
#pragma unroll
        for (int j = 0; j < 8; ++j)
            tmp[j] = f32_to_bf16_rne(tile[ch * 8 + j][oc]);
        u16* dst = out + (size_t)(ct + oc) * R + rt + ch * 8;
        ushort4 lo = {tmp[0], tmp[1], tmp[2], tmp[3]};
        ushort4 hi = {tmp[4], tmp[5], tmp[6], tmp[7]};
        *(ushort4*)dst = lo;
        *(ushort4*)(dst + 4) = hi;
    }
}

__global__ void prepass(const float* __restrict__ x,  u16* __restrict__ x_bf,
                        const float* __restrict__ W1, u16* __restrict__ W1t,
                        const float* __restrict__ W2, u16* __restrict__ W2t) {
    __shared__ float tile[32][33];
    const int b = blockIdx.x;
    if (b < 4096) {
        int i = b * 256 + threadIdx.x;
        float4 v = ((const float4*)x)[i];
        ushort4 o;
        o.x = f32_to_bf16_rne(v.x); o.y = f32_to_bf16_rne(v.y);
        o.z = f32_to_bf16_rne(v.z); o.w = f32_to_bf16_rne(v.w);
        ((ushort4*)x_bf)[i] = o;
    } else if (b < 8192) {
        int t = b - 4096;                       // W1: R=1024, C=4096
        transpose_tile(W1, W1t, NIN, NHID, t & 127, t >> 7, tile);
    } else {
        int t = b - 8192;                       // W2: R=4096, C=1024
        transpose_tile(W2, W2t, NHID, NOUT, t & 31, t >> 5, tile);
    }
}

// ---------------- GEMM1: 256x128 tile, 512 thr, BK=64, swizzled LDS ---------
__global__ __launch_bounds__(512) void gemm_bt_relu(
    const u16* __restrict__ A, const u16* __restrict__ Bt,
    const float* __restrict__ bias, u16* __restrict__ outp,
    int M, int N, int K)
{
    constexpr int MI = 4, NI = 4;
    __shared__ __align__(16) u16 smemA[256 * 64];   // 32 KB
    __shared__ __align__(16) u16 smemB[128 * 64];   // 16 KB

    const int bid = blockIdx.x;
    const int cxcd = bid & 7;
    const int j    = bid >> 3;                      // 0..63
    const int bx   = ((cxcd & 3) << 3) + (j & 7);   // 0..31
    const int by   = ((cxcd >> 2) << 3) + (j >> 3); // 0..15

    const int tid  = threadIdx.x;
    const int lane = tid & 63;
    const int wave = tid >> 6;                      // 0..7
    const int rowBase = by * 256;
    const int colBase = bx * 128;
    const int wrow = (wave >> 1) * 64;
    const int wcol = (wave & 1) * 64;

    f32x4 acc[MI][NI] = {};

    const int srow    = lane >> 3;
    const int chunkSw = (lane & 7) ^ srow;
    const int gcol    = chunkSw * 8;
    const int fr = lane & 15;
    const int fq = lane >> 4;
    const int sw = fr & 7;

    for (int k0 = 0; k0 < K; k0 += 64) {
        __syncthreads();
#pragma unroll
        for (int t = 0; t < 4; ++t) {               // A: 32 regions
            int region = wave * 4 + t;
            int arow = rowBase + region * 8 + srow;
            const u16* g = A + (size_t)arow * K + k0 + gcol;
            __builtin_amdgcn_global_load_lds(
                (const __attribute__((address_space(1))) u32*)g,
                (__attribute__((address_space(3))) u32*)(smemA + region * 512),
                16, 0, 0);
        }
#pragma unroll
        for (int t = 0; t < 2; ++t) {               // B: 16 regions
            int region = wave * 2 + t;
            int brow = colBase + region * 8 + srow;
            const u16* g = Bt + (size_t)brow * K + k0 + gcol;
            __builtin_amdgcn_global_load_lds(
                (const __attribute__((address_space(1))) u32*)g,
                (__attribute__((address_space(3))) u32*)(smemB + region * 512),
                16, 0, 0);
        }
        __builtin_amdgcn_s_waitcnt(0);
        __syncthreads();

#pragma unroll
        for (int s = 0; s < 2; ++s) {
            const int co = ((s * 4 + fq) ^ sw) * 16;
            const char* aB = (const char*)smemA + (wrow + fr) * 128 + co;
            const char* bB = (const char*)smemB + (wcol + fr) * 128 + co;
            bf16x8 af[MI], bfv[NI];
#pragma unroll
            for (int mi = 0; mi < MI; ++mi)
                af[mi] = *(const bf16x8*)(aB + mi * 2048);
#pragma unroll
            for (int ni = 0; ni < NI; ++ni)
                bfv[ni] = *(const bf16x8*)(bB + ni * 2048);
#pragma unroll
            for (int mi = 0; mi < MI; ++mi)
#pragma unroll
                for (int ni = 0; ni < NI; ++ni)
                    acc[mi][ni] = __builtin_amdgcn_mfma_f32_16x16x32_bf16(
                        af[mi], bfv[ni], acc[mi][ni], 0, 0, 0);
        }
    }

    // C/D layout: col = lane&15, row = (lane>>4)*4 + reg  [m89/m91]
    const int col0 = colBase + wcol + fr;
    const int row0 = rowBase + wrow + (fq << 2);
#pragma unroll
    for (int ni = 0; ni < NI; ++ni) {
        const int col = col0 + ni * 16;
        const float bv = bias[col];
#pragma unroll
        for (int mi = 0; mi < MI; ++mi) {
            const int row = row0 + mi * 16;
#pragma unroll
            for (int r = 0; r < 4; ++r) {
                float v = acc[mi][ni][r] + bv;
                v = v > 0.f ? v : 0.f;
                outp[(size_t)(row + r) * N + col] = f32_to_bf16_rne(v);
            }
        }
    }
}

// ------ GEMM2: 256x128, split-K S=4, bf16 partials, fused last-block reduce -
// Each z writes its bf16 partial to pbf[z*M*N], release-fences, bumps the
// per-tile counter (device-scope). The 4th arrival acquire-fences, reads the
// other 3 partials, adds its own fp32 acc + bias, writes d_out. cnt[] must be
// zeroed before launch (hipMemsetAsync).
__global__ __launch_bounds__(512) void gemm2_splitk(
    const u16* __restrict__ A, const u16* __restrict__ Bt,
    const float* __restrict__ bias, u16* __restrict__ pbf,
    float* __restrict__ out0, u32* __restrict__ cnt,
    int M, int N, int K, int Kchunk)
{
    constexpr int MI = 4, NI = 4;
    __shared__ __align__(16) u16 smemA[256 * 64];   // 32 KB
    __shared__ __align__(16) u16 smemB[128 * 64];   // 16 KB
    __shared__ int lastFlag;

    const int bid = blockIdx.x;
    const int cxcd = bid & 7;
    const int j    = bid >> 3;                      // 0..63
    const int z    = cxcd >> 1;                     // 0..3
    const int bx   = j & 7;                         // 0..7
    const int by   = ((cxcd & 1) << 3) + (j >> 3);  // 0..15

    const int tid  = threadIdx.x;
    const int lane = tid & 63;
    const int wave = tid >> 6;
    const int rowBase = by * 256;
    const int colBase = bx * 128;
    const int kBeg = z * Kchunk;
    const int kEnd = kBeg + Kchunk;
    const int wrow = (wave >> 1) * 64;
    const int wcol = (wave & 1) * 64;

    f32x4 acc[MI][NI] = {};

    const int srow    = lane >> 3;
    const int chunkSw = (lane & 7) ^ srow;
    const int gcol    = chunkSw * 8;
    const int fr = lane & 15;
    const int fq = lane >> 4;
    const int sw = fr & 7;

    for (int k0 = kBeg; k0 < kEnd; k0 += 64) {
        __syncthreads();
#pragma unroll
        for (int t = 0; t < 4; ++t) {
            int region = wave * 4 + t;
            int arow = rowBase + region * 8 + srow;
            const u16* g = A + (size_t)arow * K + k0 + gcol;
            __builtin_amdgcn_global_load_lds(
                (const __attribute__((address_space(1))) u32*)g,
                (__attribute__((address_space(3))) u32*)(smemA + region * 512),
                16, 0, 0);
        }
#pragma unroll
        for (int t = 0; t < 2; ++t) {
            int region = wave * 2 + t;
            int brow = colBase + region * 8 + srow;
            const u16* g = Bt + (size_t)brow * K + k0 + gcol;
            __builtin_amdgcn_global_load_lds(
                (const __attribute__((address_space(1))) u32*)g,
                (__attribute__((address_space(3))) u32*)(smemB + region * 512),
                16, 0, 0);
        }
        __builtin_amdgcn_s_waitcnt(0);
        __syncthreads();

#pragma unroll
        for (int s = 0; s < 2; ++s) {
            const int co = ((s * 4 + fq) ^ sw) * 16;
            const char* aB = (const char*)smemA + (wrow + fr) * 128 + co;
            const char* bB = (const char*)smemB + (wcol + fr) * 128 + co;
            bf16x8 af[MI], bfv[NI];
#pragma unroll
            for (int mi = 0; mi < MI; ++mi)
                af[mi] = *(const bf16x8*)(aB + mi * 2048);
#pragma unroll
            for (int ni = 0; ni < NI; ++ni)
                bfv[ni] = *(const bf16x8*)(bB + ni * 2048);
#pragma unroll
            for (int mi = 0; mi < MI; ++mi)
#pragma unroll
                for (int ni = 0; ni < NI; ++ni)
                    acc[mi][ni] = __builtin_amdgcn_mfma_f32_16x16x32_bf16(
                        af[mi], bfv[ni], acc[mi][ni], 0, 0, 0);
        }
    }

    const size_t MN = (size_t)M * N;
    u16* myp = pbf + (size_t)z * MN;
    const int col0 = colBase + wcol + fr;
    const int row0 = rowBase + wrow + (fq << 2);

    // 1) store own bf16 partial
#pragma unroll
    for (int ni = 0; ni < NI; ++ni) {
        const int col = col0 + ni * 16;
#pragma unroll
        for (int mi = 0; mi < MI; ++mi) {
            const int row = row0 + mi * 16;
#pragma unroll
            for (int r = 0; r < 4; ++r)
                myp[(size_t)(row + r) * N + col] =
                    f32_to_bf16_rne(acc[mi][ni][r]);
        }
    }

    // 2) release + count arrivals for this output tile
    __threadfence();                         // agent-scope release
    __syncthreads();                         // all threads' stores issued
    if (tid == 0)
        lastFlag = (int)atomicAdd(&cnt[by * 8 + bx], 1u);
    __syncthreads();
    if (lastFlag != 3) return;

    // 3) last arrival: acquire, combine 3 foreign partials + own acc + bias
    __threadfence();                         // agent-scope acquire
#pragma unroll
    for (int ni = 0; ni < NI; ++ni) {
        const int col = col0 + ni * 16;
        const float bv = bias[col];
#pragma unroll
        for (int mi = 0; mi < MI; ++mi) {
            const int row = row0 + mi * 16;
#pragma unroll
            for (int r = 0; r < 4; ++r) {
                const size_t idx = (size_t)(row + r) * N + col;
                float v = acc[mi][ni][r] + bv;
#pragma unroll
                for (int zz = 0; zz < 4; ++zz)
                    if (zz != z) v += bf16_to_f32(pbf[zz * MN + idx]);
                out0[idx] = v;
            }
        }
    }
}

extern "C" void kernel_launch(void* const* d_in, const int* in_sizes, int n_in,
                              void* d_out, int out_size, void* d_ws, size_t ws_size,
                              hipStream_t stream) {
    const float* x  = (const float*)d_in[0];
    const float* W1 = (const float*)d_in[1];
    const float* b1 = (const float*)d_in[2];
    const float* W2 = (const float*)d_in[3];
    const float* b2 = (const float*)d_in[4];

    char* ws = (char*)d_ws;
    const size_t MB = 1024 * 1024;
    u16* W2t  = (u16*)(ws + 0 * MB);    //  8 MB
    u16* h_bf = (u16*)(ws + 8 * MB);    // 32 MB
    u16* x_bf = (u16*)(ws + 40 * MB);   //  8 MB
    u16* W1t  = (u16*)(ws + 48 * MB);   //  8 MB
    u16* pbf  = (u16*)(ws + 56 * MB);   // 4 x 8 MB bf16 split-K partials
    u32* cnt  = (u32*)(ws + 88 * MB);   // 128 tile counters

    // zero the tile counters (512 B, graph-legal memset node)
    hipMemsetAsync(cnt, 0, 128 * sizeof(u32), stream);

    // fused pre-pass: cast x + transpose W1 + transpose W2
    prepass<<<12288, 256, 0, stream>>>(x, x_bf, W1, W1t, W2, W2t);

    // h = relu(x @ W1 + b1)   [M=4096, N=4096, K=1024], 256x128 tile
    gemm_bt_relu<<<512, 512, 0, stream>>>(
        x_bf, W1t, b1, h_bf, BDIM, NHID, NIN);

    // y = h @ W2 + b2  [M=4096, N=1024, K=4096], S=4, fused last-block reduce
    gemm2_splitk<<<512, 512, 0, stream>>>(
        h_bf, W2t, b2, pbf, (float*)d_out, cnt, BDIM, NOUT, NHID, NHID / 4);
}

// Round 13
// 171.037 us; speedup vs baseline: 2.9362x; 2.9362x over previous
//
#include <hip/hip_runtime.h>
#include <stdint.h>

// Problem dims (fixed by reference)
#define BDIM  4096
#define NIN   1024
#define NHID  4096
#define NOUT  1024

typedef unsigned short u16;
typedef unsigned int   u32;
typedef __attribute__((ext_vector_type(8))) __bf16 bf16x8;
typedef __attribute__((ext_vector_type(4))) float  f32x4;

__device__ __forceinline__ u16 f32_to_bf16_rne(float f) {
    u32 u = __builtin_bit_cast(u32, f);
    u = (u + 0x7fffu + ((u >> 16) & 1u)) >> 16;
    return (u16)u;
}
__device__ __forceinline__ float bf16_to_f32(u16 h) {
    u32 u = ((u32)h) << 16;
    return __builtin_bit_cast(float, u);
}

// ------------- fused pre-pass: cast x + transpose W1 + transpose W2 ---------
__device__ __forceinline__ void transpose_tile(
    const float* __restrict__ in, u16* __restrict__ out,
    int R, int C, int bx, int by, float (*tile)[33]) {
    const int rt = by * 32, ct = bx * 32;
    const int tid = threadIdx.x;
    {
        const int r  = tid >> 3;
        const int c4 = (tid & 7) * 4;
        float4 v = *(const float4*)(in + (size_t)(rt + r) * C + ct + c4);
        tile[r][c4 + 0] = v.x; tile[r][c4 + 1] = v.y;
        tile[r][c4 + 2] = v.z; tile[r][c4 + 3] = v.w;
    }
    __syncthreads();
    if (tid < 128) {
        const int oc = tid >> 2;
        const int ch = tid & 3;
        u16 tmp[8];
#pragma unroll
        for (int j = 0; j < 8; ++j)
            tmp[j] = f32_to_bf16_rne(tile[ch * 8 + j][oc]);
        u16* dst = out + (size_t)(ct + oc) * R + rt + ch * 8;
        ushort4 lo = {tmp[0], tmp[1], tmp[2], tmp[3]};
        ushort4 hi = {tmp[4], tmp[5], tmp[6], tmp[7]};
        *(ushort4*)dst = lo;
        *(ushort4*)(dst + 4) = hi;
    }
}

__global__ void prepass(const float* __restrict__ x,  u16* __restrict__ x_bf,
                        const float* __restrict__ W1, u16* __restrict__ W1t,
                        const float* __restrict__ W2, u16* __restrict__ W2t) {
    __shared__ float tile[32][33];
    const int b = blockIdx.x;
    if (b < 4096) {
        int i = b * 256 + threadIdx.x;
        float4 v = ((const float4*)x)[i];
        ushort4 o;
        o.x = f32_to_bf16_rne(v.x); o.y = f32_to_bf16_rne(v.y);
        o.z = f32_to_bf16_rne(v.z); o.w = f32_to_bf16_rne(v.w);
        ((ushort4*)x_bf)[i] = o;
    } else if (b < 8192) {
        int t = b - 4096;                       // W1: R=1024, C=4096
        transpose_tile(W1, W1t, NIN, NHID, t & 127, t >> 7, tile);
    } else {
        int t = b - 8192;                       // W2: R=4096, C=1024
        transpose_tile(W2, W2t, NHID, NOUT, t & 31, t >> 5, tile);
    }
}

// ---------------- GEMM1: 256x128 tile, 512 thr, BK=64, swizzled LDS ---------
__global__ __launch_bounds__(512) void gemm_bt_relu(
    const u16* __restrict__ A, const u16* __restrict__ Bt,
    const float* __restrict__ bias, u16* __restrict__ outp,
    int M, int N, int K)
{
    constexpr int MI = 4, NI = 4;
    __shared__ __align__(16) u16 smemA[256 * 64];   // 32 KB
    __shared__ __align__(16) u16 smemB[128 * 64];   // 16 KB

    const int bid = blockIdx.x;
    const int cxcd = bid & 7;
    const int j    = bid >> 3;                      // 0..63
    const int bx   = ((cxcd & 3) << 3) + (j & 7);   // 0..31
    const int by   = ((cxcd >> 2) << 3) + (j >> 3); // 0..15

    const int tid  = threadIdx.x;
    const int lane = tid & 63;
    const int wave = tid >> 6;                      // 0..7
    const int rowBase = by * 256;
    const int colBase = bx * 128;
    const int wrow = (wave >> 1) * 64;
    const int wcol = (wave & 1) * 64;

    f32x4 acc[MI][NI] = {};

    const int srow    = lane >> 3;
    const int chunkSw = (lane & 7) ^ srow;
    const int gcol    = chunkSw * 8;
    const int fr = lane & 15;
    const int fq = lane >> 4;
    const int sw = fr & 7;

    for (int k0 = 0; k0 < K; k0 += 64) {
        __syncthreads();
#pragma unroll
        for (int t = 0; t < 4; ++t) {               // A: 32 regions
            int region = wave * 4 + t;
            int arow = rowBase + region * 8 + srow;
            const u16* g = A + (size_t)arow * K + k0 + gcol;
            __builtin_amdgcn_global_load_lds(
                (const __attribute__((address_space(1))) u32*)g,
                (__attribute__((address_space(3))) u32*)(smemA + region * 512),
                16, 0, 0);
        }
#pragma unroll
        for (int t = 0; t < 2; ++t) {               // B: 16 regions
            int region = wave * 2 + t;
            int brow = colBase + region * 8 + srow;
            const u16* g = Bt + (size_t)brow * K + k0 + gcol;
            __builtin_amdgcn_global_load_lds(
                (const __attribute__((address_space(1))) u32*)g,
                (__attribute__((address_space(3))) u32*)(smemB + region * 512),
                16, 0, 0);
        }
        __builtin_amdgcn_s_waitcnt(0);
        __syncthreads();

#pragma unroll
        for (int s = 0; s < 2; ++s) {
            const int co = ((s * 4 + fq) ^ sw) * 16;
            const char* aB = (const char*)smemA + (wrow + fr) * 128 + co;
            const char* bB = (const char*)smemB + (wcol + fr) * 128 + co;
            bf16x8 af[MI], bfv[NI];
#pragma unroll
            for (int mi = 0; mi < MI; ++mi)
                af[mi] = *(const bf16x8*)(aB + mi * 2048);
#pragma unroll
            for (int ni = 0; ni < NI; ++ni)
                bfv[ni] = *(const bf16x8*)(bB + ni * 2048);
#pragma unroll
            for (int mi = 0; mi < MI; ++mi)
#pragma unroll
                for (int ni = 0; ni < NI; ++ni)
                    acc[mi][ni] = __builtin_amdgcn_mfma_f32_16x16x32_bf16(
                        af[mi], bfv[ni], acc[mi][ni], 0, 0, 0);
        }
    }

    // C/D layout: col = lane&15, row = (lane>>4)*4 + reg  [m89/m91]
    const int col0 = colBase + wcol + fr;
    const int row0 = rowBase + wrow + (fq << 2);
#pragma unroll
    for (int ni = 0; ni < NI; ++ni) {
        const int col = col0 + ni * 16;
        const float bv = bias[col];
#pragma unroll
        for (int mi = 0; mi < MI; ++mi) {
            const int row = row0 + mi * 16;
#pragma unroll
            for (int r = 0; r < 4; ++r) {
                float v = acc[mi][ni][r] + bv;
                v = v > 0.f ? v : 0.f;
                outp[(size_t)(row + r) * N + col] = f32_to_bf16_rne(v);
            }
        }
    }
}

// ---------------- GEMM2: 256x128 tile, 512 thr, split-K S=4, bf16 partials --
// All four z-slices write raw bf16 partials to pbf[z*M*N]; bias in reduce.
__global__ __launch_bounds__(512) void gemm2_splitk(
    const u16* __restrict__ A, const u16* __restrict__ Bt,
    u16* __restrict__ pbf, int M, int N, int K, int Kchunk)
{
    constexpr int MI = 4, NI = 4;
    __shared__ __align__(16) u16 smemA[256 * 64];   // 32 KB
    __shared__ __align__(16) u16 smemB[128 * 64];   // 16 KB

    const int bid = blockIdx.x;
    const int cxcd = bid & 7;
    const int j    = bid >> 3;                      // 0..63
    const int z    = cxcd >> 1;                     // 0..3
    const int bx   = j & 7;                         // 0..7
    const int by   = ((cxcd & 1) << 3) + (j >> 3);  // 0..15

    const int tid  = threadIdx.x;
    const int lane = tid & 63;
    const int wave = tid >> 6;
    const int rowBase = by * 256;
    const int colBase = bx * 128;
    const int kBeg = z * Kchunk;
    const int kEnd = kBeg + Kchunk;
    const int wrow = (wave >> 1) * 64;
    const int wcol = (wave & 1) * 64;

    f32x4 acc[MI][NI] = {};

    const int srow    = lane >> 3;
    const int chunkSw = (lane & 7) ^ srow;
    const int gcol    = chunkSw * 8;
    const int fr = lane & 15;
    const int fq = lane >> 4;
    const int sw = fr & 7;

    for (int k0 = kBeg; k0 < kEnd; k0 += 64) {
        __syncthreads();
#pragma unroll
        for (int t = 0; t < 4; ++t) {
            int region = wave * 4 + t;
            int arow = rowBase + region * 8 + srow;
            const u16* g = A + (size_t)arow * K + k0 + gcol;
            __builtin_amdgcn_global_load_lds(
                (const __attribute__((address_space(1))) u32*)g,
                (__attribute__((address_space(3))) u32*)(smemA + region * 512),
                16, 0, 0);
        }
#pragma unroll
        for (int t = 0; t < 2; ++t) {
            int region = wave * 2 + t;
            int brow = colBase + region * 8 + srow;
            const u16* g = Bt + (size_t)brow * K + k0 + gcol;
            __builtin_amdgcn_global_load_lds(
                (const __attribute__((address_space(1))) u32*)g,
                (__attribute__((address_space(3))) u32*)(smemB + region * 512),
                16, 0, 0);
        }
        __builtin_amdgcn_s_waitcnt(0);
        __syncthreads();

#pragma unroll
        for (int s = 0; s < 2; ++s) {
            const int co = ((s * 4 + fq) ^ sw) * 16;
            const char* aB = (const char*)smemA + (wrow + fr) * 128 + co;
            const char* bB = (const char*)smemB + (wcol + fr) * 128 + co;
            bf16x8 af[MI], bfv[NI];
#pragma unroll
            for (int mi = 0; mi < MI; ++mi)
                af[mi] = *(const bf16x8*)(aB + mi * 2048);
#pragma unroll
            for (int ni = 0; ni < NI; ++ni)
                bfv[ni] = *(const bf16x8*)(bB + ni * 2048);
#pragma unroll
            for (int mi = 0; mi < MI; ++mi)
#pragma unroll
                for (int ni = 0; ni < NI; ++ni)
                    acc[mi][ni] = __builtin_amdgcn_mfma_f32_16x16x32_bf16(
                        af[mi], bfv[ni], acc[mi][ni], 0, 0, 0);
        }
    }

    u16* outp = pbf + (size_t)z * M * N;
    const int col0 = colBase + wcol + fr;
    const int row0 = rowBase + wrow + (fq << 2);
#pragma unroll
    for (int ni = 0; ni < NI; ++ni) {
        const int col = col0 + ni * 16;
#pragma unroll
        for (int mi = 0; mi < MI; ++mi) {
            const int row = row0 + mi * 16;
#pragma unroll
            for (int r = 0; r < 4; ++r)
                outp[(size_t)(row + r) * N + col] =
                    f32_to_bf16_rne(acc[mi][ni][r]);
        }
    }
}

// ------- split-K reduce: out = sum of 4 bf16 partials + bias (fp32 out) -----
__global__ void splitk_reduce(float* __restrict__ out0,
                              const u16* __restrict__ pbf,
                              const float* __restrict__ bias,
                              int n4, int nCols4) {
    int i = blockIdx.x * blockDim.x + threadIdx.x;
    if (i >= n4) return;
    const size_t MN = (size_t)n4 * 4;
    float4 v = ((const float4*)bias)[i & (nCols4 - 1)];
#pragma unroll
    for (int s = 0; s < 4; ++s) {
        ushort4 q = ((const ushort4*)(pbf + s * MN))[i];
        v.x += bf16_to_f32(q.x); v.y += bf16_to_f32(q.y);
        v.z += bf16_to_f32(q.z); v.w += bf16_to_f32(q.w);
    }
    ((float4*)out0)[i] = v;
}

extern "C" void kernel_launch(void* const* d_in, const int* in_sizes, int n_in,
                              void* d_out, int out_size, void* d_ws, size_t ws_size,
                              hipStream_t stream) {
    const float* x  = (const float*)d_in[0];
    const float* W1 = (const float*)d_in[1];
    const float* b1 = (const float*)d_in[2];
    const float* W2 = (const float*)d_in[3];
    const float* b2 = (const float*)d_in[4];

    char* ws = (char*)d_ws;
    const size_t MB = 1024 * 1024;
    u16* W2t  = (u16*)(ws + 0 * MB);    //  8 MB
    u16* h_bf = (u16*)(ws + 8 * MB);    // 32 MB
    u16* x_bf = (u16*)(ws + 40 * MB);   //  8 MB
    u16* W1t  = (u16*)(ws + 48 * MB);   //  8 MB
    u16* pbf  = (u16*)(ws + 56 * MB);   // 4 x 8 MB bf16 split-K partials

    // fused pre-pass: cast x + transpose W1 + transpose W2
    prepass<<<12288, 256, 0, stream>>>(x, x_bf, W1, W1t, W2, W2t);

    // h = relu(x @ W1 + b1)   [M=4096, N=4096, K=1024], 256x128 tile
    gemm_bt_relu<<<512, 512, 0, stream>>>(
        x_bf, W1t, b1, h_bf, BDIM, NHID, NIN);

    // y = h @ W2 + b2         [M=4096, N=1024, K=4096], split-K S=4, bf16 parts
    gemm2_splitk<<<512, 512, 0, stream>>>(
        h_bf, W2t, pbf, BDIM, NOUT, NHID, NHID / 4);

    int rn4 = BDIM * NOUT / 4;
    splitk_reduce<<<(rn4 + 255) / 256, 256, 0, stream>>>(
        (float*)d_out, pbf, b2, rn4, NOUT / 4);
}